// Round 1
// baseline (373.185 us; speedup 1.0000x reference)
//
#include <hip/hip_runtime.h>

// Problem constants (fixed by the reference setup_inputs):
// feat  [N=16, C=256, H=128, W=128] fp32
// logit [N=16, CLS=9, H=128, W=128] fp32
// out   [N, C, CLS] fp32 (broadcast of [C, CLS] protos)
#define HWN   16384            // H*W
#define NB    16               // batch
#define CH    256              // channels
#define CLS   9                // classes
#define PTOT  (NB * HWN)       // 262144 pixels
#define LBLK  (PTOT / 1024)    // 256 label blocks (4 px/thread, 256 thr)
#define SBLK  (NB * CH)        // 4096 rows in the partial buffer
#define CGRP  (CH / 4)         // 64 channel-groups of 4 per n
#define SUMB  (NB * CGRP)      // 1024 sum blocks

typedef float v4f __attribute__((ext_vector_type(4)));

// ---------------------------------------------------------------------------
// K1: per-pixel argmax over CLS logits. 4 pixels/thread -> float4 logit loads
// (PLAIN cached loads: nt hint suspected of capping streaming BW), packed
// uint label store. Per-block histogram to a distinct slot (no global
// atomics, no init needed).
// ---------------------------------------------------------------------------
__global__ __launch_bounds__(256) void label_kernel(
    const float* __restrict__ logit,
    unsigned int* __restrict__ labels4,   // [PTOT/4] packed 4 labels/uint
    int* __restrict__ hist)               // [LBLK][CLS]
{
    __shared__ int h[CLS];
    if (threadIdx.x < CLS) h[threadIdx.x] = 0;
    __syncthreads();

    const int t  = blockIdx.x * 256 + threadIdx.x;  // packed-uint index
    const int p0 = t << 2;                          // first pixel of the 4
    const int n  = p0 >> 14;                        // / HWN (same n for all 4)
    const int hw = p0 & (HWN - 1);
    const v4f* __restrict__ base = (const v4f*)(logit + (size_t)n * CLS * HWN + hw);

    v4f best = base[0];
    int b0 = 0, b1 = 0, b2 = 0, b3 = 0;
#pragma unroll
    for (int k = 1; k < CLS; ++k) {
        const v4f v = base[(size_t)k * (HWN / 4)];
        if (v[0] > best[0]) { best[0] = v[0]; b0 = k; }  // strict > == jnp.argmax tie-break
        if (v[1] > best[1]) { best[1] = v[1]; b1 = k; }
        if (v[2] > best[2]) { best[2] = v[2]; b2 = k; }
        if (v[3] > best[3]) { best[3] = v[3]; b3 = k; }
    }
    labels4[t] = (unsigned)b0 | ((unsigned)b1 << 8) |
                 ((unsigned)b2 << 16) | ((unsigned)b3 << 24);

    atomicAdd(&h[b0], 1); atomicAdd(&h[b1], 1);
    atomicAdd(&h[b2], 1); atomicAdd(&h[b3], 1);
    __syncthreads();
    if (threadIdx.x < CLS) hist[blockIdx.x * CLS + threadIdx.x] = h[threadIdx.x];
}

// ---------------------------------------------------------------------------
// K2 (restructured): one block per (n, channel-group-of-4). Each iteration a
// thread loads ONE label-uint (4 pixels) and FOUR float4s (same 4 pixels, 4
// different channel slabs). The 36 per-pixel class masks are computed once
// and amortized across the 4 channels -> ~15 VALU ops/element instead of 27,
// and selects become straight v_fma. The asm barrier on each mask blocks the
// compiler from folding x*mask back into per-channel cndmask chains.
// Plain cached loads throughout (no nt).
// ---------------------------------------------------------------------------
__global__ __launch_bounds__(256) void sum_kernel(
    const float* __restrict__ feat,
    const unsigned int* __restrict__ labels4,
    float* __restrict__ partial)   // [SBLK][CLS]
{
    const int b  = blockIdx.x;          // [0, SUMB)
    const int n  = b >> 6;              // / CGRP
    const int cg = b & (CGRP - 1);
    const int c0 = (n << 8) + (cg << 2);   // first of 4 feat slab rows

    const v4f* __restrict__ f0 = (const v4f*)(feat + (size_t)(c0 + 0) * HWN);
    const v4f* __restrict__ f1 = (const v4f*)(feat + (size_t)(c0 + 1) * HWN);
    const v4f* __restrict__ f2 = (const v4f*)(feat + (size_t)(c0 + 2) * HWN);
    const v4f* __restrict__ f3 = (const v4f*)(feat + (size_t)(c0 + 3) * HWN);
    const unsigned int* __restrict__ l4 = labels4 + (size_t)n * (HWN / 4);

    float acc[4][CLS];
#pragma unroll
    for (int c = 0; c < 4; ++c)
#pragma unroll
        for (int k = 0; k < CLS; ++k) acc[c][k] = 0.0f;

    // HWN/4 = 4096 float4 groups, 256 threads -> 16 iterations each.
#pragma unroll 2
    for (int i = threadIdx.x; i < HWN / 4; i += 256) {
        const unsigned int lu = l4[i];
        const v4f x0 = f0[i];
        const v4f x1 = f1[i];
        const v4f x2 = f2[i];
        const v4f x3 = f3[i];

        float m[4][CLS];                 // per-pixel one-hot as float
#pragma unroll
        for (int j = 0; j < 4; ++j) {
            const int l = (lu >> (8 * j)) & 255;
#pragma unroll
            for (int k = 0; k < CLS; ++k) {
                float mm = (l == k) ? 1.0f : 0.0f;
                asm("" : "+v"(mm));      // keep as value: force fma, not cndmask
                m[j][k] = mm;
            }
        }

#pragma unroll
        for (int k = 0; k < CLS; ++k) {
            acc[0][k] += x0[0] * m[0][k] + x0[1] * m[1][k]
                       + x0[2] * m[2][k] + x0[3] * m[3][k];
            acc[1][k] += x1[0] * m[0][k] + x1[1] * m[1][k]
                       + x1[2] * m[2][k] + x1[3] * m[3][k];
            acc[2][k] += x2[0] * m[0][k] + x2[1] * m[1][k]
                       + x2[2] * m[2][k] + x2[3] * m[3][k];
            acc[3][k] += x3[0] * m[0][k] + x3[1] * m[1][k]
                       + x3[2] * m[2][k] + x3[3] * m[3][k];
        }
    }

    // Cross-thread reduce: LDS transpose [256][37] (pad -> <=2-way bank alias,
    // free), 36 lanes column-sum with 4-way ILP, one coalesced partial write.
    __shared__ float red[256][37];
#pragma unroll
    for (int c = 0; c < 4; ++c)
#pragma unroll
        for (int k = 0; k < CLS; ++k) red[threadIdx.x][c * CLS + k] = acc[c][k];
    __syncthreads();

    if (threadIdx.x < 36) {
        float s0 = 0.0f, s1 = 0.0f, s2 = 0.0f, s3 = 0.0f;
#pragma unroll 8
        for (int t = 0; t < 256; t += 4) {
            s0 += red[t + 0][threadIdx.x];
            s1 += red[t + 1][threadIdx.x];
            s2 += red[t + 2][threadIdx.x];
            s3 += red[t + 3][threadIdx.x];
        }
        const int c = threadIdx.x / CLS;
        const int k = threadIdx.x - c * CLS;
        partial[(size_t)(c0 + c) * CLS + k] = (s0 + s1) + (s2 + s3);
    }
}

// ---------------------------------------------------------------------------
// K3: reduce 16 n-partials per (c,k), divide by counts (reduced from hist),
// broadcast-write out[n][c][k]. 9 blocks x 256 threads = 2304 = CH*CLS.
// ---------------------------------------------------------------------------
__global__ __launch_bounds__(256) void finalize_kernel(
    const float* __restrict__ partial,  // [SBLK][CLS]
    const int* __restrict__ hist,       // [LBLK][CLS]
    float* __restrict__ out)            // [NB][CH][CLS]
{
    // --- counts: tree-reduce the 256 per-block histograms (redundant/block) ---
    __shared__ int sc[256][CLS];        // 9216 B, stride 9 -> conflict-benign
    const int t = threadIdx.x;
#pragma unroll
    for (int k = 0; k < CLS; ++k) sc[t][k] = hist[t * CLS + k];
    __syncthreads();
#pragma unroll
    for (int off = 128; off > 0; off >>= 1) {
        if (t < off) {
#pragma unroll
            for (int k = 0; k < CLS; ++k) sc[t][k] += sc[t + off][k];
        }
        __syncthreads();
    }

    // --- protos + broadcast ---
    const int idx = blockIdx.x * 256 + t;          // [0, CH*CLS)
    if (idx >= CH * CLS) return;
    const int k = idx % CLS;

    float acc = 0.0f;
#pragma unroll
    for (int np = 0; np < NB; ++np)                // coalesced: stride CH*CLS
        acc += partial[np * (CH * CLS) + idx];

    const float proto = acc / (float)max(sc[0][k], 1);
#pragma unroll
    for (int np = 0; np < NB; ++np)
        out[np * (CH * CLS) + idx] = proto;        // coalesced per round
}

// ---------------------------------------------------------------------------
extern "C" void kernel_launch(void* const* d_in, const int* in_sizes, int n_in,
                              void* d_out, int out_size, void* d_ws, size_t ws_size,
                              hipStream_t stream)
{
    const float* feat  = (const float*)d_in[0];
    const float* logit = (const float*)d_in[1];
    // d_in[2] is cls_num (== 9, fixed by the problem); hardcoded as CLS.

    // Workspace layout — every word fully overwritten before read, so the
    // harness's 0xAA poison needs no memset:
    //   [0,       147456)  float partial[SBLK][CLS]
    //   [147456,  156672)  int   hist[LBLK][CLS]
    //   [156928,  419072)  uint  labels4[PTOT/4]   (256 B-aligned start)
    char* ws = (char*)d_ws;
    float*        partial = (float*)ws;
    int*          hist    = (int*)(ws + 147456);
    unsigned int* labels4 = (unsigned int*)(ws + 156928);

    label_kernel<<<LBLK, 256, 0, stream>>>(logit, labels4, hist);
    sum_kernel<<<SUMB, 256, 0, stream>>>(feat, labels4, partial);
    finalize_kernel<<<(CH * CLS + 255) / 256, 256, 0, stream>>>(partial, hist, (float*)d_out);
}

// Round 2
// 352.408 us; speedup vs baseline: 1.0590x; 1.0590x over previous
//
#include <hip/hip_runtime.h>

// Problem constants (fixed by the reference setup_inputs):
// feat  [N=16, C=256, H=128, W=128] fp32
// logit [N=16, CLS=9, H=128, W=128] fp32
// out   [N, C, CLS] fp32 (broadcast of [C, CLS] protos)
//
// PERF MODEL (round-2 analysis): the timed window shares HBM with two
// ~1.07 GB harness poison fills of the workspace. Combined traffic
// (2.147 GB poison + ~0.28 GB ours) at the ~6.85 TB/s mixed achievable
// ceiling = ~352 us -> this kernel's 352.9 us IS the combined roofline.
// Round-1 falsification: halving VALU/elem + dropping nt REGRESSED +20 us
// (feat allocating in L2 evicted the labels -> +~140 MB HBM re-fetch).
// nt on the streamed-once feat/logit is traffic protection, not a BW hint.
#define HWN   16384            // H*W
#define NB    16               // batch
#define CH    256              // channels
#define CLS   9                // classes
#define PTOT  (NB * HWN)       // 262144 pixels
#define LBLK  (PTOT / 1024)    // 256 label blocks (4 px/thread, 256 thr)
#define SBLK  (NB * CH)        // 4096 sum blocks

typedef float v4f __attribute__((ext_vector_type(4)));

// ---------------------------------------------------------------------------
// K1: per-pixel argmax over CLS logits. 4 pixels/thread -> float4 logit loads
// (non-temporal: logit is read exactly once), packed uint label store.
// Per-block histogram to a distinct slot (no global atomics, no init needed).
// ---------------------------------------------------------------------------
__global__ __launch_bounds__(256) void label_kernel(
    const float* __restrict__ logit,
    unsigned int* __restrict__ labels4,   // [PTOT/4] packed 4 labels/uint
    int* __restrict__ hist)               // [LBLK][CLS]
{
    __shared__ int h[CLS];
    if (threadIdx.x < CLS) h[threadIdx.x] = 0;
    __syncthreads();

    const int t  = blockIdx.x * 256 + threadIdx.x;  // packed-uint index
    const int p0 = t << 2;                          // first pixel of the 4
    const int n  = p0 >> 14;                        // / HWN (same n for all 4)
    const int hw = p0 & (HWN - 1);
    const v4f* base = (const v4f*)(logit + (size_t)n * CLS * HWN + hw);

    v4f best = __builtin_nontemporal_load(base);
    int b0 = 0, b1 = 0, b2 = 0, b3 = 0;
#pragma unroll
    for (int k = 1; k < CLS; ++k) {
        const v4f v = __builtin_nontemporal_load(base + (size_t)k * (HWN / 4));
        if (v[0] > best[0]) { best[0] = v[0]; b0 = k; }  // strict > == jnp.argmax tie-break
        if (v[1] > best[1]) { best[1] = v[1]; b1 = k; }
        if (v[2] > best[2]) { best[2] = v[2]; b2 = k; }
        if (v[3] > best[3]) { best[3] = v[3]; b3 = k; }
    }
    labels4[t] = (unsigned)b0 | ((unsigned)b1 << 8) |
                 ((unsigned)b2 << 16) | ((unsigned)b3 << 24);

    atomicAdd(&h[b0], 1); atomicAdd(&h[b1], 1);
    atomicAdd(&h[b2], 1); atomicAdd(&h[b3], 1);
    __syncthreads();
    if (threadIdx.x < CLS) hist[blockIdx.x * CLS + threadIdx.x] = h[threadIdx.x];
}

// ---------------------------------------------------------------------------
// K2: one block per (n,c) slab of 16384 contiguous floats. Non-temporal
// float4 feat loads (feat is streamed exactly once -> don't pollute L2),
// cached uint label loads (256 KiB total, L2-resident across 4096 blocks).
// Register class-bins -> wave shuffle tree -> cross-wave LDS -> per-block
// partial written to a distinct slot (no atomics, no init).
// ---------------------------------------------------------------------------
__global__ __launch_bounds__(256) void sum_kernel(
    const float* __restrict__ feat,
    const unsigned int* __restrict__ labels4,
    float* __restrict__ partial)   // [SBLK][CLS]
{
    const int b = blockIdx.x;            // b = n*CH + c == feat slab index
    const int n = b >> 8;

    const v4f*          f4 = (const v4f*)(feat + (size_t)b * HWN);
    const unsigned int* l4 = labels4 + (size_t)n * (HWN / 4);

    float s[CLS];
#pragma unroll
    for (int k = 0; k < CLS; ++k) s[k] = 0.0f;

    // 4096 float4 chunks, 256 threads -> 16 iterations each; unroll 8 keeps
    // 8 dwordx4 loads in flight per thread.
#pragma unroll 8
    for (int i = threadIdx.x; i < HWN / 4; i += 256) {
        const v4f          v  = __builtin_nontemporal_load(&f4[i]);
        const unsigned int lu = l4[i];
#pragma unroll
        for (int j = 0; j < 4; ++j) {
            const float x = v[j];
            const int   l = (lu >> (8 * j)) & 255;
#pragma unroll
            for (int k = 0; k < CLS; ++k)
                s[k] += (l == k) ? x : 0.0f;
        }
    }

    // Wave(64) shuffle-tree reduction per class, then cross-wave via LDS.
#pragma unroll
    for (int k = 0; k < CLS; ++k)
        for (int off = 32; off > 0; off >>= 1)
            s[k] += __shfl_down(s[k], off, 64);

    __shared__ float wsum[4][CLS];
    const int wave = threadIdx.x >> 6;
    if ((threadIdx.x & 63) == 0) {
#pragma unroll
        for (int k = 0; k < CLS; ++k) wsum[wave][k] = s[k];
    }
    __syncthreads();

    if (threadIdx.x < CLS) {
        const int k = threadIdx.x;
        partial[b * CLS + k] = wsum[0][k] + wsum[1][k] + wsum[2][k] + wsum[3][k];
    }
}

// ---------------------------------------------------------------------------
// K3: reduce 16 n-partials per (c,k), divide by counts (reduced from hist),
// broadcast-write out[n][c][k]. 9 blocks x 256 threads = 2304 = CH*CLS.
// ---------------------------------------------------------------------------
__global__ __launch_bounds__(256) void finalize_kernel(
    const float* __restrict__ partial,  // [SBLK][CLS]
    const int* __restrict__ hist,       // [LBLK][CLS]
    float* __restrict__ out)            // [NB][CH][CLS]
{
    // --- counts: tree-reduce the 256 per-block histograms (redundant/block) ---
    __shared__ int sc[256][CLS];        // 9216 B, stride 9 -> conflict-benign
    const int t = threadIdx.x;
#pragma unroll
    for (int k = 0; k < CLS; ++k) sc[t][k] = hist[t * CLS + k];
    __syncthreads();
#pragma unroll
    for (int off = 128; off > 0; off >>= 1) {
        if (t < off) {
#pragma unroll
            for (int k = 0; k < CLS; ++k) sc[t][k] += sc[t + off][k];
        }
        __syncthreads();
    }

    // --- protos + broadcast ---
    const int idx = blockIdx.x * 256 + t;          // [0, CH*CLS)
    if (idx >= CH * CLS) return;
    const int k = idx % CLS;

    float acc = 0.0f;
#pragma unroll
    for (int np = 0; np < NB; ++np)                // coalesced: stride CH*CLS
        acc += partial[np * (CH * CLS) + idx];

    const float proto = acc / (float)max(sc[0][k], 1);
#pragma unroll
    for (int np = 0; np < NB; ++np)
        out[np * (CH * CLS) + idx] = proto;        // coalesced per round
}

// ---------------------------------------------------------------------------
extern "C" void kernel_launch(void* const* d_in, const int* in_sizes, int n_in,
                              void* d_out, int out_size, void* d_ws, size_t ws_size,
                              hipStream_t stream)
{
    const float* feat  = (const float*)d_in[0];
    const float* logit = (const float*)d_in[1];
    // d_in[2] is cls_num (== 9, fixed by the problem); hardcoded as CLS.

    // Workspace layout — every word fully overwritten before read, so the
    // harness's 0xAA poison needs no memset:
    //   [0,       147456)  float partial[SBLK][CLS]
    //   [147456,  156672)  int   hist[LBLK][CLS]
    //   [156928,  419072)  uint  labels4[PTOT/4]   (256 B-aligned start)
    char* ws = (char*)d_ws;
    float*        partial = (float*)ws;
    int*          hist    = (int*)(ws + 147456);
    unsigned int* labels4 = (unsigned int*)(ws + 156928);

    label_kernel<<<LBLK, 256, 0, stream>>>(logit, labels4, hist);
    sum_kernel<<<SBLK, 256, 0, stream>>>(feat, labels4, partial);
    finalize_kernel<<<(CH * CLS + 255) / 256, 256, 0, stream>>>(partial, hist, (float*)d_out);
}